// Round 7
// baseline (83.153 us; speedup 1.0000x reference)
//
#include <hip/hip_runtime.h>
#include <stdint.h>

// QTIP hybrid codebook dequant:
//   c    = uint32(code), c < 2^16
//   t    = (c+1)*c            (only low 16 bits matter; u24 mul exact)
//   sign = bit15(t)           (flips component 0 only)
//   idx  = (t >> 6) & 511
//   out[2i] = lut[idx].x ^sign ; out[2i+1] = lut[idx].y
//
// Memory-bound: 128 MiB read + 256 MiB write => ~64 us floor at 6.3 TB/s.
// R6 change (single-variable vs R5): double-buffered group pipeline.
// Issue the NEXT group's 8 loads BEFORE the current group's stores, so a
// wave's load-waits never force prior HBM stores to retire (vmcnt is a
// shared, in-order counter for loads AND stores on CDNA). R5 interleaved
// stores(k) before loads(k+1), pulling store retirement into the load
// dependence chain once per group.
// Lessons kept: nt on loads only (R4: nt-stores = -40%); dense stores.

typedef int   v2i __attribute__((ext_vector_type(2)));
typedef float v4f __attribute__((ext_vector_type(4)));

__device__ __forceinline__ float2 qtip_one(const float2* __restrict__ slut, uint32_t c) {
    uint32_t t = __umul24(c + 1u, c);   // exact: c < 2^16
    float2 g = slut[(t >> 6) & 511u];
    float2 r;
    r.x = __uint_as_float(__float_as_uint(g.x) ^ ((t << 16) & 0x80000000u));
    r.y = g.y;
    return r;
}

__device__ __forceinline__ v4f qtip_two(const float2* __restrict__ slut, v2i c2) {
    float2 e0 = qtip_one(slut, (uint32_t)c2.x);
    float2 e1 = qtip_one(slut, (uint32_t)c2.y);
    v4f r = {e0.x, e0.y, e1.x, e1.y};
    return r;
}

__global__ __launch_bounds__(256, 8) void qtip_lut_kernel(
    const int* __restrict__ codes,
    const float* __restrict__ lut,
    float* __restrict__ out,
    int n)  // number of codes
{
    // Stage the 4 KiB LUT into LDS (512 x float2).
    __shared__ float2 slut[512];
    for (int i = threadIdx.x; i < 512; i += 256)
        slut[i] = reinterpret_cast<const float2*>(lut)[i];
    __syncthreads();

    const int n2 = n >> 1;                 // int2 count (2^24 here)
    const int stride = gridDim.x * blockDim.x;
    const int tid0 = blockIdx.x * blockDim.x + threadIdx.x;
    const v2i* __restrict__ codes2 = reinterpret_cast<const v2i*>(codes);
    v4f* __restrict__ out4 = reinterpret_cast<v4f*>(out);

    const int iters = n2 / stride;         // uniform across threads (32 here)
    const int ngroups = iters >> 3;        // groups of 8 rounds (4 here)
    int i = tid0;

    if (ngroups > 0) {
        // Prologue: load group 0.
        v2i c[8];
#pragma unroll
        for (int u = 0; u < 8; ++u)
            c[u] = __builtin_nontemporal_load(&codes2[i + u * stride]);

        // Steady state: loads(g+1) issued BEFORE stores(g).
        for (int g = 0; g + 1 < ngroups; ++g) {
            const int inext = i + 8 * stride;
            v2i cn[8];
#pragma unroll
            for (int u = 0; u < 8; ++u)
                cn[u] = __builtin_nontemporal_load(&codes2[inext + u * stride]);
#pragma unroll
            for (int u = 0; u < 8; ++u)
                out4[i + u * stride] = qtip_two(slut, c[u]);
#pragma unroll
            for (int u = 0; u < 8; ++u)
                c[u] = cn[u];
            i = inext;
        }
        // Epilogue: last group, no prefetch.
#pragma unroll
        for (int u = 0; u < 8; ++u)
            out4[i + u * stride] = qtip_two(slut, c[u]);
        i += 8 * stride;
    }
    // Leftover uniform rounds (iters % 8) — not hit for the main config.
    for (int it = ngroups << 3; it < iters; ++it) {
        v2i c2 = __builtin_nontemporal_load(&codes2[i]);
        out4[i] = qtip_two(slut, c2);
        i += stride;
    }
    // Residual int2s past the uniform region (at most one partial round).
    for (int j = iters * stride + tid0; j < n2; j += stride) {
        v2i c2 = __builtin_nontemporal_load(&codes2[j]);
        out4[j] = qtip_two(slut, c2);
    }
    // Scalar tail (n odd) — not hit for this problem (n = 2^25).
    for (int k = (n2 << 1) + tid0; k < n; k += stride) {
        float2 e = qtip_one(slut, (uint32_t)codes[k]);
        out[2 * k]     = e.x;
        out[2 * k + 1] = e.y;
    }
}

extern "C" void kernel_launch(void* const* d_in, const int* in_sizes, int n_in,
                              void* d_out, int out_size, void* d_ws, size_t ws_size,
                              hipStream_t stream) {
    const int* codes = (const int*)d_in[0];
    const float* lut = (const float*)d_in[1];
    float* out = (float*)d_out;
    const int n = in_sizes[0];  // 8192*4096 codes

    int n2 = n >> 1;
    int blocks = (n2 + 255) / 256;
    if (blocks > 2048) blocks = 2048;  // 8 blocks/CU x 256 CUs, 32 waves/CU
    if (blocks < 1) blocks = 1;

    qtip_lut_kernel<<<blocks, 256, 0, stream>>>(codes, lut, out, n);
}

// Round 8
// 71.765 us; speedup vs baseline: 1.1587x; 1.1587x over previous
//
#include <hip/hip_runtime.h>
#include <stdint.h>

// QTIP hybrid codebook dequant:
//   c    = uint32(code), c < 2^16
//   t    = (c+1)*c            (only low 16 bits matter; u24 mul exact)
//   sign = bit15(t)           (flips component 0 only)
//   idx  = (t >> 6) & 511
//   out[2i] = lut[idx].x ^sign ; out[2i+1] = lut[idx].y
//
// Memory-bound: 128 MiB read + 256 MiB write => ~64 us floor at 6.3 TB/s.
// R7 change (single-variable vs R5): grid 2048 -> 8192 blocks. With 2048
// blocks (= exactly 8/CU, 32 uniform rounds/thread, zero slack) any CU
// dealt 9 blocks instead of 8 becomes a +12.5% straggler — matching the
// observed 75 vs ~67 us gap. 8192 short blocks let the dispatcher refill
// early-finishing CUs (imbalance tail 1/8 -> 1/32 of runtime).
// Lessons kept: nt on loads only (R4: nt-stores -40%); dense 1KiB/wave
// stores; 8-deep load batch; NO prefetch pipeline (R6: -11%, spills).

typedef int   v2i __attribute__((ext_vector_type(2)));
typedef float v4f __attribute__((ext_vector_type(4)));

__device__ __forceinline__ float2 qtip_one(const float2* __restrict__ slut, uint32_t c) {
    uint32_t t = __umul24(c + 1u, c);   // exact: c < 2^16
    float2 g = slut[(t >> 6) & 511u];
    float2 r;
    r.x = __uint_as_float(__float_as_uint(g.x) ^ ((t << 16) & 0x80000000u));
    r.y = g.y;
    return r;
}

__device__ __forceinline__ v4f qtip_two(const float2* __restrict__ slut, v2i c2) {
    float2 e0 = qtip_one(slut, (uint32_t)c2.x);
    float2 e1 = qtip_one(slut, (uint32_t)c2.y);
    v4f r = {e0.x, e0.y, e1.x, e1.y};
    return r;
}

__global__ __launch_bounds__(256, 8) void qtip_lut_kernel(
    const int* __restrict__ codes,
    const float* __restrict__ lut,
    float* __restrict__ out,
    int n)  // number of codes
{
    // Stage the 4 KiB LUT into LDS (512 x float2).
    __shared__ float2 slut[512];
    for (int i = threadIdx.x; i < 512; i += 256)
        slut[i] = reinterpret_cast<const float2*>(lut)[i];
    __syncthreads();

    const int n2 = n >> 1;                 // int2 count (2^24 here)
    const int stride = gridDim.x * blockDim.x;
    const int tid0 = blockIdx.x * blockDim.x + threadIdx.x;
    const v2i* __restrict__ codes2 = reinterpret_cast<const v2i*>(codes);
    v4f* __restrict__ out4 = reinterpret_cast<v4f*>(out);

    const int iters = n2 / stride;         // uniform across threads (8 here)
    int i = tid0;
    int it = 0;

    // Main: 8 independent 8B loads in flight before any use.
    for (; it + 8 <= iters; it += 8) {
        v2i c[8];
#pragma unroll
        for (int u = 0; u < 8; ++u)
            c[u] = __builtin_nontemporal_load(&codes2[i + u * stride]);
#pragma unroll
        for (int u = 0; u < 8; ++u) {
            out4[i + u * stride] = qtip_two(slut, c[u]);
        }
        i += 8 * stride;
    }
    // Leftover uniform rounds (iters % 8).
    for (; it < iters; ++it) {
        v2i c2 = __builtin_nontemporal_load(&codes2[i]);
        out4[i] = qtip_two(slut, c2);
        i += stride;
    }
    // Residual int2s past the uniform region (at most one partial round).
    for (int j = iters * stride + tid0; j < n2; j += stride) {
        v2i c2 = __builtin_nontemporal_load(&codes2[j]);
        out4[j] = qtip_two(slut, c2);
    }
    // Scalar tail (n odd) — not hit for this problem (n = 2^25).
    for (int k = (n2 << 1) + tid0; k < n; k += stride) {
        float2 e = qtip_one(slut, (uint32_t)codes[k]);
        out[2 * k]     = e.x;
        out[2 * k + 1] = e.y;
    }
}

extern "C" void kernel_launch(void* const* d_in, const int* in_sizes, int n_in,
                              void* d_out, int out_size, void* d_ws, size_t ws_size,
                              hipStream_t stream) {
    const int* codes = (const int*)d_in[0];
    const float* lut = (const float*)d_in[1];
    float* out = (float*)d_out;
    const int n = in_sizes[0];  // 8192*4096 codes

    int n2 = n >> 1;
    int blocks = (n2 + 255) / 256;
    if (blocks > 8192) blocks = 8192;  // 32 short blocks/CU -> dispatcher
                                       // load-balances; tail 1/32 not 1/8
    if (blocks < 1) blocks = 1;

    qtip_lut_kernel<<<blocks, 256, 0, stream>>>(codes, lut, out, n);
}

// Round 9
// 70.744 us; speedup vs baseline: 1.1754x; 1.0144x over previous
//
#include <hip/hip_runtime.h>
#include <stdint.h>

// QTIP hybrid codebook dequant:
//   c    = uint32(code), c < 2^16
//   t    = (c+1)*c            (only low 16 bits matter; u24 mul exact)
//   sign = bit15(t)           (flips component 0 only)
//   idx  = (t >> 6) & 511
//   out[2i] = lut[idx].x ^sign ; out[2i+1] = lut[idx].y
//
// Memory-bound: 128 MiB read + 256 MiB write. Pure-write memset = 7.0 TB/s,
// 1:1 copy = 6.3 TB/s; this 1R:2W mix plausibly ceilings ~5.6-6.0 TB/s.
// R8 change (single-variable vs R7): grid 16384 blocks / 4 rounds per
// thread / 4-deep load batch. Halves the drain-tail granularity (R7's
// 2048->8192 step gave +4%; this tests whether tail is still the residual).
// Arithmetic says VALU ~40%, LDS ~30%, 35x TLP latency slack -> if this is
// null we are at the mixed-stream HBM ceiling.
// Lessons kept: nt on loads only (R4: nt-stores -40%); dense 1KiB/wave
// stores; no reg prefetch pipeline (R6: -11%).

typedef int   v2i __attribute__((ext_vector_type(2)));
typedef float v4f __attribute__((ext_vector_type(4)));

__device__ __forceinline__ float2 qtip_one(const float2* __restrict__ slut, uint32_t c) {
    uint32_t t = __umul24(c + 1u, c);   // exact: c < 2^16
    float2 g = slut[(t >> 6) & 511u];
    float2 r;
    r.x = __uint_as_float(__float_as_uint(g.x) ^ ((t << 16) & 0x80000000u));
    r.y = g.y;
    return r;
}

__device__ __forceinline__ v4f qtip_two(const float2* __restrict__ slut, v2i c2) {
    float2 e0 = qtip_one(slut, (uint32_t)c2.x);
    float2 e1 = qtip_one(slut, (uint32_t)c2.y);
    v4f r = {e0.x, e0.y, e1.x, e1.y};
    return r;
}

__global__ __launch_bounds__(256, 8) void qtip_lut_kernel(
    const int* __restrict__ codes,
    const float* __restrict__ lut,
    float* __restrict__ out,
    int n)  // number of codes
{
    // Stage the 4 KiB LUT into LDS (512 x float2).
    __shared__ float2 slut[512];
    for (int i = threadIdx.x; i < 512; i += 256)
        slut[i] = reinterpret_cast<const float2*>(lut)[i];
    __syncthreads();

    const int n2 = n >> 1;                 // int2 count (2^24 here)
    const int stride = gridDim.x * blockDim.x;
    const int tid0 = blockIdx.x * blockDim.x + threadIdx.x;
    const v2i* __restrict__ codes2 = reinterpret_cast<const v2i*>(codes);
    v4f* __restrict__ out4 = reinterpret_cast<v4f*>(out);

    const int iters = n2 / stride;         // uniform across threads (4 here)
    int i = tid0;
    int it = 0;

    // Main: 4 independent 8B loads in flight before any use.
    for (; it + 4 <= iters; it += 4) {
        v2i c[4];
#pragma unroll
        for (int u = 0; u < 4; ++u)
            c[u] = __builtin_nontemporal_load(&codes2[i + u * stride]);
#pragma unroll
        for (int u = 0; u < 4; ++u) {
            out4[i + u * stride] = qtip_two(slut, c[u]);
        }
        i += 4 * stride;
    }
    // Leftover uniform rounds (iters % 4).
    for (; it < iters; ++it) {
        v2i c2 = __builtin_nontemporal_load(&codes2[i]);
        out4[i] = qtip_two(slut, c2);
        i += stride;
    }
    // Residual int2s past the uniform region (at most one partial round).
    for (int j = iters * stride + tid0; j < n2; j += stride) {
        v2i c2 = __builtin_nontemporal_load(&codes2[j]);
        out4[j] = qtip_two(slut, c2);
    }
    // Scalar tail (n odd) — not hit for this problem (n = 2^25).
    for (int k = (n2 << 1) + tid0; k < n; k += stride) {
        float2 e = qtip_one(slut, (uint32_t)codes[k]);
        out[2 * k]     = e.x;
        out[2 * k + 1] = e.y;
    }
}

extern "C" void kernel_launch(void* const* d_in, const int* in_sizes, int n_in,
                              void* d_out, int out_size, void* d_ws, size_t ws_size,
                              hipStream_t stream) {
    const int* codes = (const int*)d_in[0];
    const float* lut = (const float*)d_in[1];
    float* out = (float*)d_out;
    const int n = in_sizes[0];  // 8192*4096 codes

    int n2 = n >> 1;
    int blocks = (n2 + 255) / 256;
    if (blocks > 16384) blocks = 16384;  // 64 short blocks/CU: finer
                                         // load-balance tail (~1/64)
    if (blocks < 1) blocks = 1;

    qtip_lut_kernel<<<blocks, 256, 0, stream>>>(codes, lut, out, n);
}